// Round 1
// baseline (2051.177 us; speedup 1.0000x reference)
//
#include <hip/hip_runtime.h>
#include <hip/hip_bf16.h>

// Problem dims (fixed for QuantLlamaMLP_549755813920)
#define T_TOK 4096   // tokens = 2*2048
#define KDIM  4096   // in_features
#define IDIM  11008  // intermediate
#define ODIM  4096   // out_features

typedef __bf16 bf16x8 __attribute__((ext_vector_type(8)));
typedef float  f32x4  __attribute__((ext_vector_type(4)));
typedef unsigned short ushort_t;

// async global->LDS, 16B per lane; LDS dest = wave-uniform base + lane*16
__device__ __forceinline__ void glds16(const void* g, void* l) {
  __builtin_amdgcn_global_load_lds(
      (const __attribute__((address_space(1))) void*)g,
      (__attribute__((address_space(3))) void*)l, 16, 0, 0);
}

// ---------------- x: f32 -> bf16 ----------------
__global__ void k_f32_to_bf16(const float4* __restrict__ x,
                              ushort4* __restrict__ o, int n4) {
  int i = blockIdx.x * 256 + threadIdx.x;
  if (i >= n4) return;
  float4 v = x[i];
  __hip_bfloat16 b0 = __float2bfloat16(v.x);
  __hip_bfloat16 b1 = __float2bfloat16(v.y);
  __hip_bfloat16 b2 = __float2bfloat16(v.z);
  __hip_bfloat16 b3 = __float2bfloat16(v.w);
  ushort4 r;
  r.x = *(ushort_t*)&b0; r.y = *(ushort_t*)&b1;
  r.z = *(ushort_t*)&b2; r.w = *(ushort_t*)&b3;
  o[i] = r;
}

// ---------------- dequant int4 + transpose: W[k][n] -> Wt[n][k] bf16 -------
// qw: [K, N/8] int32, sc: [K/128, N] f32, qz: [K/128, N/8] int32
// grid: (N/64, K/64), block 256. 64x64 tile via LDS transpose.
__global__ void k_dequant_t(const int* __restrict__ qw,
                            const float* __restrict__ sc,
                            const int* __restrict__ qz,
                            __hip_bfloat16* __restrict__ wt,
                            int K, int N) {
  __shared__ __align__(16) __hip_bfloat16 tile[64][72];  // [n][k], padded
  const int n0 = blockIdx.x * 64;
  const int k0 = blockIdx.y * 64;
  const int t  = threadIdx.x;
  const int Nw = N >> 3;
  const int grp = k0 >> 7;  // 64-tile always within one 128-group
  const int jj = t & 7;     // word column within the 8-word span
  const int zword = qz[(size_t)grp * Nw + (n0 >> 3) + jj];
  float s[8];
#pragma unroll
  for (int i = 0; i < 8; ++i) s[i] = sc[(size_t)grp * N + n0 + jj * 8 + i];
#pragma unroll
  for (int r = 0; r < 2; ++r) {
    const int kk = (t >> 3) + r * 32;
    const int word = qw[(size_t)(k0 + kk) * Nw + (n0 >> 3) + jj];
#pragma unroll
    for (int i = 0; i < 8; ++i) {
      const int q = (word >> (4 * i)) & 0xF;
      const int z = (zword >> (4 * i)) & 0xF;
      tile[jj * 8 + i][kk] = __float2bfloat16((float)(q - z) * s[i]);
    }
  }
  __syncthreads();
  const int n  = t >> 2;
  const int kc = (t & 3) * 16;
  const float4* src = (const float4*)&tile[n][kc];
  float4* dst = (float4*)(wt + (size_t)(n0 + n) * K + k0 + kc);
  dst[0] = src[0];
  dst[1] = src[1];
}

// ---------------- GEMM: C[M,N] = A[M,K] @ Bt[N,K]^T  (m97 structure) ------
// EPI 0: C bf16 = acc          (up pass -> h buffer)
// EPI 1: C bf16 = silu(acc)*C  (gate pass, reads u from h, writes h)
// EPI 2: C f32  = acc          (down pass -> d_out)
template <int EPI>
__global__ __launch_bounds__(256, 2)
void k_gemm_bt(const __hip_bfloat16* __restrict__ A,
               const __hip_bfloat16* __restrict__ B,
               void* __restrict__ Cv, int M, int N, int K) {
  __shared__ __align__(16) __hip_bfloat16 As[128 * 32];
  __shared__ __align__(16) __hip_bfloat16 Bs[128 * 32];
  const int n0 = blockIdx.x * 128;
  const int m0 = blockIdx.y * 128;
  const int t = threadIdx.x;
  const int w = t >> 6;
  const int lane = t & 63;
  const int quad = lane >> 4;
  const int lm = lane & 15;
  const int wm = w >> 1;
  const int wn = w & 1;
  f32x4 acc[4][4] = {};

  // staging: wave w covers rows [w*32, w*32+32); lane -> (row, 16B chunk)
  const int lrow = lane >> 2;
  const int lkc  = (lane & 3) * 8;  // bf16 elements
  const __hip_bfloat16* Ag0 = A + (size_t)(m0 + w * 32 + lrow) * K + lkc;
  const __hip_bfloat16* Ag1 = Ag0 + (size_t)16 * K;
  const __hip_bfloat16* Bg0 = B + (size_t)(n0 + w * 32 + lrow) * K + lkc;
  const __hip_bfloat16* Bg1 = Bg0 + (size_t)16 * K;
  __hip_bfloat16* lA0 = &As[(w * 32) * 32];
  __hip_bfloat16* lA1 = &As[(w * 32 + 16) * 32];
  __hip_bfloat16* lB0 = &Bs[(w * 32) * 32];
  __hip_bfloat16* lB1 = &Bs[(w * 32 + 16) * 32];

  for (int k0 = 0; k0 < K; k0 += 32) {
    __syncthreads();
    glds16(Ag0 + k0, lA0);
    glds16(Ag1 + k0, lA1);
    glds16(Bg0 + k0, lB0);
    glds16(Bg1 + k0, lB1);
    __syncthreads();  // compiler emits vmcnt(0) drain here
    bf16x8 af[4], bfr[4];
#pragma unroll
    for (int mi = 0; mi < 4; ++mi)
      af[mi] = *(const bf16x8*)&As[(wm * 64 + mi * 16 + lm) * 32 + quad * 8];
#pragma unroll
    for (int ni = 0; ni < 4; ++ni)
      bfr[ni] = *(const bf16x8*)&Bs[(wn * 64 + ni * 16 + lm) * 32 + quad * 8];
#pragma unroll
    for (int mi = 0; mi < 4; ++mi)
#pragma unroll
      for (int ni = 0; ni < 4; ++ni)
        acc[mi][ni] = __builtin_amdgcn_mfma_f32_16x16x32_bf16(
            af[mi], bfr[ni], acc[mi][ni], 0, 0, 0);
  }

  // epilogue: C/D layout col=lane&15, row=quad*4+reg (m89-verified)
#pragma unroll
  for (int mi = 0; mi < 4; ++mi)
#pragma unroll
    for (int ni = 0; ni < 4; ++ni)
#pragma unroll
      for (int r = 0; r < 4; ++r) {
        const int row = m0 + wm * 64 + mi * 16 + quad * 4 + r;
        const int col = n0 + wn * 64 + ni * 16 + lm;
        const float v = acc[mi][ni][r];
        if (EPI == 0) {
          ((__hip_bfloat16*)Cv)[(size_t)row * N + col] = __float2bfloat16(v);
        } else if (EPI == 1) {
          __hip_bfloat16* H = (__hip_bfloat16*)Cv;
          const float u = __bfloat162float(H[(size_t)row * N + col]);
          const float sg = v / (1.0f + __expf(-v));
          H[(size_t)row * N + col] = __float2bfloat16(sg * u);
        } else {
          ((float*)Cv)[(size_t)row * N + col] = v;
        }
      }
}

extern "C" void kernel_launch(void* const* d_in, const int* in_sizes, int n_in,
                              void* d_out, int out_size, void* d_ws, size_t ws_size,
                              hipStream_t stream) {
  const float* x   = (const float*)d_in[0];
  const int*   gqw = (const int*)d_in[1];
  const float* gsc = (const float*)d_in[2];
  const int*   gqz = (const int*)d_in[3];
  const int*   uqw = (const int*)d_in[4];
  const float* usc = (const float*)d_in[5];
  const int*   uqz = (const int*)d_in[6];
  const int*   dqw = (const int*)d_in[7];
  const float* dsc = (const float*)d_in[8];
  const int*   dqz = (const int*)d_in[9];
  float* out = (float*)d_out;

  // ws layout (214 MB total):
  //   xb   : T_TOK*KDIM bf16      = 33,554,432 B
  //   wbuf : IDIM*KDIM bf16       = 90,177,536 B (reused for up/gate/down^T)
  //   h    : T_TOK*IDIM bf16      = 90,177,536 B
  char* ws = (char*)d_ws;
  __hip_bfloat16* xb   = (__hip_bfloat16*)ws;
  __hip_bfloat16* wbuf = (__hip_bfloat16*)(ws + 33554432);
  __hip_bfloat16* h    = (__hip_bfloat16*)(ws + 33554432 + 90177536);

  k_f32_to_bf16<<<16384, 256, 0, stream>>>((const float4*)x, (ushort4*)xb,
                                           (T_TOK * KDIM) / 4);

  dim3 dqg(IDIM / 64, KDIM / 64);    // (172, 64)
  dim3 dqd(ODIM / 64, IDIM / 64);    // (64, 172)
  dim3 g1(IDIM / 128, T_TOK / 128);  // (86, 32)
  dim3 g2(ODIM / 128, T_TOK / 128);  // (32, 32)

  // up: u = x @ Wu^T  -> h (bf16)
  k_dequant_t<<<dqg, 256, 0, stream>>>(uqw, usc, uqz, wbuf, KDIM, IDIM);
  k_gemm_bt<0><<<g1, 256, 0, stream>>>(xb, wbuf, (void*)h, T_TOK, IDIM, KDIM);
  // gate: h = silu(x @ Wg^T) * h
  k_dequant_t<<<dqg, 256, 0, stream>>>(gqw, gsc, gqz, wbuf, KDIM, IDIM);
  k_gemm_bt<1><<<g1, 256, 0, stream>>>(xb, wbuf, (void*)h, T_TOK, IDIM, KDIM);
  // down: out = h @ Wd^T (f32)
  k_dequant_t<<<dqd, 256, 0, stream>>>(dqw, dsc, dqz, wbuf, IDIM, ODIM);
  k_gemm_bt<2><<<g2, 256, 0, stream>>>(h, wbuf, (void*)out, T_TOK, ODIM, IDIM);
}

// Round 2
// 1628.066 us; speedup vs baseline: 1.2599x; 1.2599x over previous
//
#include <hip/hip_runtime.h>
#include <hip/hip_bf16.h>

// Problem dims (fixed for QuantLlamaMLP_549755813920)
#define T_TOK 4096   // tokens = 2*2048
#define KDIM  4096   // in_features
#define IDIM  11008  // intermediate
#define ODIM  4096   // out_features

typedef __bf16 bf16x8 __attribute__((ext_vector_type(8)));
typedef float  f32x4  __attribute__((ext_vector_type(4)));
typedef unsigned short ushort_t;

// async global->LDS, 16B per lane; LDS dest = wave-uniform base + lane*16
__device__ __forceinline__ void glds16(const void* g, void* l) {
  __builtin_amdgcn_global_load_lds(
      (const __attribute__((address_space(1))) void*)g,
      (__attribute__((address_space(3))) void*)l, 16, 0, 0);
}

// ---------------- x: f32 -> bf16 ----------------
__global__ void k_f32_to_bf16(const float4* __restrict__ x,
                              ushort4* __restrict__ o, int n4) {
  int i = blockIdx.x * 256 + threadIdx.x;
  if (i >= n4) return;
  float4 v = x[i];
  __hip_bfloat16 b0 = __float2bfloat16(v.x);
  __hip_bfloat16 b1 = __float2bfloat16(v.y);
  __hip_bfloat16 b2 = __float2bfloat16(v.z);
  __hip_bfloat16 b3 = __float2bfloat16(v.w);
  ushort4 r;
  r.x = *(ushort_t*)&b0; r.y = *(ushort_t*)&b1;
  r.z = *(ushort_t*)&b2; r.w = *(ushort_t*)&b3;
  o[i] = r;
}

// ---------------- dequant int4 + transpose: W[k][n] -> Wt[n][k] bf16 -------
// qw: [K, N/8] int32, sc: [K/128, N] f32, qz: [K/128, N/8] int32
// grid: (N/64, K/64), block 256. 64x64 tile via LDS transpose.
__global__ void k_dequant_t(const int* __restrict__ qw,
                            const float* __restrict__ sc,
                            const int* __restrict__ qz,
                            __hip_bfloat16* __restrict__ wt,
                            int K, int N) {
  __shared__ __align__(16) __hip_bfloat16 tile[64][72];  // [n][k], padded
  const int n0 = blockIdx.x * 64;
  const int k0 = blockIdx.y * 64;
  const int t  = threadIdx.x;
  const int Nw = N >> 3;
  const int grp = k0 >> 7;  // 64-tile always within one 128-group
  const int jj = t & 7;     // word column within the 8-word span
  const int zword = qz[(size_t)grp * Nw + (n0 >> 3) + jj];
  float s[8];
#pragma unroll
  for (int i = 0; i < 8; ++i) s[i] = sc[(size_t)grp * N + n0 + jj * 8 + i];
#pragma unroll
  for (int r = 0; r < 2; ++r) {
    const int kk = (t >> 3) + r * 32;
    const int word = qw[(size_t)(k0 + kk) * Nw + (n0 >> 3) + jj];
#pragma unroll
    for (int i = 0; i < 8; ++i) {
      const int q = (word >> (4 * i)) & 0xF;
      const int z = (zword >> (4 * i)) & 0xF;
      tile[jj * 8 + i][kk] = __float2bfloat16((float)(q - z) * s[i]);
    }
  }
  __syncthreads();
  const int n  = t >> 2;
  const int kc = (t & 3) * 16;
  const float4* src = (const float4*)&tile[n][kc];
  float4* dst = (float4*)(wt + (size_t)(n0 + n) * K + k0 + kc);
  dst[0] = src[0];
  dst[1] = src[1];
}

// ---------------- GEMM: C[M,N] = A[M,K] @ Bt[N,K]^T  (m97 structure) ------
// Grouped block swizzle (R2): execution order is m-fastest in bands of
// GM=16 m-blocks, sweeping n within a band. Consecutive 16 bids share one
// B slab; per-XCD (bid%8 round-robin) resident set = 2 A slabs (2 MB) +
// 1 streaming B slab (1 MB) < 4 MB L2. Cuts L2 fills ~2.2 GB -> ~1.4 GB.
// EPI 0: C bf16 = acc          (up pass -> h buffer)
// EPI 1: C bf16 = silu(acc)*C  (gate pass, reads u from h, writes h)
// EPI 2: C f32  = acc          (down pass -> d_out)
template <int EPI>
__global__ __launch_bounds__(256, 2)
void k_gemm_bt(const __hip_bfloat16* __restrict__ A,
               const __hip_bfloat16* __restrict__ B,
               void* __restrict__ Cv, int M, int N, int K) {
  __shared__ __align__(16) __hip_bfloat16 As[128 * 32];
  __shared__ __align__(16) __hip_bfloat16 Bs[128 * 32];
  // ---- grouped swizzle: bid -> (mb, nb) ----
  const int nblk = gridDim.x;                    // N/128
  const int bid  = blockIdx.y * nblk + blockIdx.x;
  const int GM   = 16;                           // band height (M/128 % 16 == 0)
  const int band_sz = GM * nblk;
  const int band = bid / band_sz;
  const int rrem = bid - band * band_sz;
  const int nb   = rrem / GM;
  const int mb   = band * GM + (rrem - nb * GM);
  const int n0 = nb * 128;
  const int m0 = mb * 128;

  const int t = threadIdx.x;
  const int w = t >> 6;
  const int lane = t & 63;
  const int quad = lane >> 4;
  const int lm = lane & 15;
  const int wm = w >> 1;
  const int wn = w & 1;
  f32x4 acc[4][4] = {};

  // staging: wave w covers rows [w*32, w*32+32); lane -> (row, 16B chunk)
  const int lrow = lane >> 2;
  const int lkc  = (lane & 3) * 8;  // bf16 elements
  const __hip_bfloat16* Ag0 = A + (size_t)(m0 + w * 32 + lrow) * K + lkc;
  const __hip_bfloat16* Ag1 = Ag0 + (size_t)16 * K;
  const __hip_bfloat16* Bg0 = B + (size_t)(n0 + w * 32 + lrow) * K + lkc;
  const __hip_bfloat16* Bg1 = Bg0 + (size_t)16 * K;
  __hip_bfloat16* lA0 = &As[(w * 32) * 32];
  __hip_bfloat16* lA1 = &As[(w * 32 + 16) * 32];
  __hip_bfloat16* lB0 = &Bs[(w * 32) * 32];
  __hip_bfloat16* lB1 = &Bs[(w * 32 + 16) * 32];

  for (int k0 = 0; k0 < K; k0 += 32) {
    __syncthreads();
    glds16(Ag0 + k0, lA0);
    glds16(Ag1 + k0, lA1);
    glds16(Bg0 + k0, lB0);
    glds16(Bg1 + k0, lB1);
    __syncthreads();  // compiler emits vmcnt(0) drain here
    bf16x8 af[4], bfr[4];
#pragma unroll
    for (int mi = 0; mi < 4; ++mi)
      af[mi] = *(const bf16x8*)&As[(wm * 64 + mi * 16 + lm) * 32 + quad * 8];
#pragma unroll
    for (int ni = 0; ni < 4; ++ni)
      bfr[ni] = *(const bf16x8*)&Bs[(wn * 64 + ni * 16 + lm) * 32 + quad * 8];
#pragma unroll
    for (int mi = 0; mi < 4; ++mi)
#pragma unroll
      for (int ni = 0; ni < 4; ++ni)
        acc[mi][ni] = __builtin_amdgcn_mfma_f32_16x16x32_bf16(
            af[mi], bfr[ni], acc[mi][ni], 0, 0, 0);
  }

  // epilogue: C/D layout col=lane&15, row=quad*4+reg (m89-verified)
#pragma unroll
  for (int mi = 0; mi < 4; ++mi)
#pragma unroll
    for (int ni = 0; ni < 4; ++ni)
#pragma unroll
      for (int r = 0; r < 4; ++r) {
        const int row = m0 + wm * 64 + mi * 16 + quad * 4 + r;
        const int col = n0 + wn * 64 + ni * 16 + lm;
        const float v = acc[mi][ni][r];
        if (EPI == 0) {
          ((__hip_bfloat16*)Cv)[(size_t)row * N + col] = __float2bfloat16(v);
        } else if (EPI == 1) {
          __hip_bfloat16* H = (__hip_bfloat16*)Cv;
          const float u = __bfloat162float(H[(size_t)row * N + col]);
          const float sg = v / (1.0f + __expf(-v));
          H[(size_t)row * N + col] = __float2bfloat16(sg * u);
        } else {
          ((float*)Cv)[(size_t)row * N + col] = v;
        }
      }
}

extern "C" void kernel_launch(void* const* d_in, const int* in_sizes, int n_in,
                              void* d_out, int out_size, void* d_ws, size_t ws_size,
                              hipStream_t stream) {
  const float* x   = (const float*)d_in[0];
  const int*   gqw = (const int*)d_in[1];
  const float* gsc = (const float*)d_in[2];
  const int*   gqz = (const int*)d_in[3];
  const int*   uqw = (const int*)d_in[4];
  const float* usc = (const float*)d_in[5];
  const int*   uqz = (const int*)d_in[6];
  const int*   dqw = (const int*)d_in[7];
  const float* dsc = (const float*)d_in[8];
  const int*   dqz = (const int*)d_in[9];
  float* out = (float*)d_out;

  // ws layout (214 MB total):
  //   xb   : T_TOK*KDIM bf16      = 33,554,432 B
  //   wbuf : IDIM*KDIM bf16       = 90,177,536 B (reused for up/gate/down^T)
  //   h    : T_TOK*IDIM bf16      = 90,177,536 B
  char* ws = (char*)d_ws;
  __hip_bfloat16* xb   = (__hip_bfloat16*)ws;
  __hip_bfloat16* wbuf = (__hip_bfloat16*)(ws + 33554432);
  __hip_bfloat16* h    = (__hip_bfloat16*)(ws + 33554432 + 90177536);

  k_f32_to_bf16<<<16384, 256, 0, stream>>>((const float4*)x, (ushort4*)xb,
                                           (T_TOK * KDIM) / 4);

  dim3 dqg(IDIM / 64, KDIM / 64);    // (172, 64)
  dim3 dqd(ODIM / 64, IDIM / 64);    // (64, 172)
  dim3 g1(IDIM / 128, T_TOK / 128);  // (86, 32)
  dim3 g2(ODIM / 128, T_TOK / 128);  // (32, 32)

  // up: u = x @ Wu^T  -> h (bf16)
  k_dequant_t<<<dqg, 256, 0, stream>>>(uqw, usc, uqz, wbuf, KDIM, IDIM);
  k_gemm_bt<0><<<g1, 256, 0, stream>>>(xb, wbuf, (void*)h, T_TOK, IDIM, KDIM);
  // gate: h = silu(x @ Wg^T) * h
  k_dequant_t<<<dqg, 256, 0, stream>>>(gqw, gsc, gqz, wbuf, KDIM, IDIM);
  k_gemm_bt<1><<<g1, 256, 0, stream>>>(xb, wbuf, (void*)h, T_TOK, IDIM, KDIM);
  // down: out = h @ Wd^T (f32)
  k_dequant_t<<<dqd, 256, 0, stream>>>(dqw, dsc, dqz, wbuf, IDIM, ODIM);
  k_gemm_bt<2><<<g2, 256, 0, stream>>>(h, wbuf, (void*)out, T_TOK, ODIM, IDIM);
}

// Round 3
// 1563.554 us; speedup vs baseline: 1.3119x; 1.0413x over previous
//
#include <hip/hip_runtime.h>
#include <hip/hip_bf16.h>

// Problem dims (fixed for QuantLlamaMLP_549755813920)
#define T_TOK 4096   // tokens = 2*2048
#define KDIM  4096   // in_features
#define IDIM  11008  // intermediate
#define ODIM  4096   // out_features

typedef __bf16 bf16x8 __attribute__((ext_vector_type(8)));
typedef float  f32x4  __attribute__((ext_vector_type(4)));
typedef unsigned short ushort_t;

// async global->LDS, 16B per lane; LDS dest = wave-uniform base + lane*16
__device__ __forceinline__ void glds16(const void* g, void* l) {
  __builtin_amdgcn_global_load_lds(
      (const __attribute__((address_space(1))) void*)g,
      (__attribute__((address_space(3))) void*)l, 16, 0, 0);
}

// ---------------- x: f32 -> bf16 ----------------
__global__ void k_f32_to_bf16(const float4* __restrict__ x,
                              ushort4* __restrict__ o, int n4) {
  int i = blockIdx.x * 256 + threadIdx.x;
  if (i >= n4) return;
  float4 v = x[i];
  __hip_bfloat16 b0 = __float2bfloat16(v.x);
  __hip_bfloat16 b1 = __float2bfloat16(v.y);
  __hip_bfloat16 b2 = __float2bfloat16(v.z);
  __hip_bfloat16 b3 = __float2bfloat16(v.w);
  ushort4 r;
  r.x = *(ushort_t*)&b0; r.y = *(ushort_t*)&b1;
  r.z = *(ushort_t*)&b2; r.w = *(ushort_t*)&b3;
  o[i] = r;
}

// ---------------- dequant int4 + transpose: W[k][n] -> Wt[n][k] bf16 -------
__global__ void k_dequant_t(const int* __restrict__ qw,
                            const float* __restrict__ sc,
                            const int* __restrict__ qz,
                            __hip_bfloat16* __restrict__ wt,
                            int K, int N) {
  __shared__ __align__(16) __hip_bfloat16 tile[64][72];  // [n][k], padded
  const int n0 = blockIdx.x * 64;
  const int k0 = blockIdx.y * 64;
  const int t  = threadIdx.x;
  const int Nw = N >> 3;
  const int grp = k0 >> 7;  // 64-tile always within one 128-group
  const int jj = t & 7;     // word column within the 8-word span
  const int zword = qz[(size_t)grp * Nw + (n0 >> 3) + jj];
  float s[8];
#pragma unroll
  for (int i = 0; i < 8; ++i) s[i] = sc[(size_t)grp * N + n0 + jj * 8 + i];
#pragma unroll
  for (int r = 0; r < 2; ++r) {
    const int kk = (t >> 3) + r * 32;
    const int word = qw[(size_t)(k0 + kk) * Nw + (n0 >> 3) + jj];
#pragma unroll
    for (int i = 0; i < 8; ++i) {
      const int q = (word >> (4 * i)) & 0xF;
      const int z = (zword >> (4 * i)) & 0xF;
      tile[jj * 8 + i][kk] = __float2bfloat16((float)(q - z) * s[i]);
    }
  }
  __syncthreads();
  const int n  = t >> 2;
  const int kc = (t & 3) * 16;
  const float4* src = (const float4*)&tile[n][kc];
  float4* dst = (float4*)(wt + (size_t)(n0 + n) * K + k0 + kc);
  dst[0] = src[0];
  dst[1] = src[1];
}

// ---------------- GEMM: C[M,N] = A[M,K] @ Bt[N,K]^T ------
// R2: grouped swizzle (bands of GM=16 m-blocks) for L2 locality.
// R3: BK=64 as two BK=32 stages per barrier pair — halves drain windows,
//     doubles MFMA per window. Each stage keeps the row-stride-64B layout
//     (bank spread preserved; glds16 linear-dest constraint satisfied).
//     LDS 32 KB x 4 blocks = 128 KB <= 160 KB; regs capped at 128 via
//     __launch_bounds__(256,4) (56 VGPR + 64 AGPR acc baseline).
// EPI 0: C bf16 = acc          (up pass -> h buffer)
// EPI 1: C bf16 = silu(acc)*C  (gate pass, reads u from h, writes h)
// EPI 2: C f32  = acc          (down pass -> d_out)
template <int EPI>
__global__ __launch_bounds__(256, 4)
void k_gemm_bt(const __hip_bfloat16* __restrict__ A,
               const __hip_bfloat16* __restrict__ B,
               void* __restrict__ Cv, int M, int N, int K) {
  __shared__ __align__(16) __hip_bfloat16 As[2][128 * 32];
  __shared__ __align__(16) __hip_bfloat16 Bs[2][128 * 32];
  // ---- grouped swizzle: bid -> (mb, nb) ----
  const int nblk = gridDim.x;                    // N/128
  const int bid  = blockIdx.y * nblk + blockIdx.x;
  const int GM   = 16;                           // band height (M/128 % 16 == 0)
  const int band_sz = GM * nblk;
  const int band = bid / band_sz;
  const int rrem = bid - band * band_sz;
  const int nb   = rrem / GM;
  const int mb   = band * GM + (rrem - nb * GM);
  const int n0 = nb * 128;
  const int m0 = mb * 128;

  const int t = threadIdx.x;
  const int w = t >> 6;
  const int lane = t & 63;
  const int quad = lane >> 4;
  const int lm = lane & 15;
  const int wm = w >> 1;
  const int wn = w & 1;
  f32x4 acc[4][4] = {};

  // staging: wave w covers rows [w*32, w*32+32); lane -> (row, 16B chunk)
  const int lrow = lane >> 2;
  const int lkc  = (lane & 3) * 8;  // bf16 elements
  const __hip_bfloat16* Ag0 = A + (size_t)(m0 + w * 32 + lrow) * K + lkc;
  const __hip_bfloat16* Ag1 = Ag0 + (size_t)16 * K;
  const __hip_bfloat16* Bg0 = B + (size_t)(n0 + w * 32 + lrow) * K + lkc;
  const __hip_bfloat16* Bg1 = Bg0 + (size_t)16 * K;
  const int lo0 = (w * 32) * 32;
  const int lo1 = (w * 32 + 16) * 32;

  for (int k0 = 0; k0 < K; k0 += 64) {
    __syncthreads();
    // stage 0: k0 .. k0+32
    glds16(Ag0 + k0, &As[0][lo0]);
    glds16(Ag1 + k0, &As[0][lo1]);
    glds16(Bg0 + k0, &Bs[0][lo0]);
    glds16(Bg1 + k0, &Bs[0][lo1]);
    // stage 1: k0+32 .. k0+64
    glds16(Ag0 + k0 + 32, &As[1][lo0]);
    glds16(Ag1 + k0 + 32, &As[1][lo1]);
    glds16(Bg0 + k0 + 32, &Bs[1][lo0]);
    glds16(Bg1 + k0 + 32, &Bs[1][lo1]);
    __syncthreads();  // single vmcnt(0) drain per 64-K
#pragma unroll
    for (int h = 0; h < 2; ++h) {
      bf16x8 af[4], bfr[4];
#pragma unroll
      for (int mi = 0; mi < 4; ++mi)
        af[mi] = *(const bf16x8*)&As[h][(wm * 64 + mi * 16 + lm) * 32 + quad * 8];
#pragma unroll
      for (int ni = 0; ni < 4; ++ni)
        bfr[ni] = *(const bf16x8*)&Bs[h][(wn * 64 + ni * 16 + lm) * 32 + quad * 8];
#pragma unroll
      for (int mi = 0; mi < 4; ++mi)
#pragma unroll
        for (int ni = 0; ni < 4; ++ni)
          acc[mi][ni] = __builtin_amdgcn_mfma_f32_16x16x32_bf16(
              af[mi], bfr[ni], acc[mi][ni], 0, 0, 0);
    }
  }

  // epilogue: C/D layout col=lane&15, row=quad*4+reg (m89-verified)
#pragma unroll
  for (int mi = 0; mi < 4; ++mi)
#pragma unroll
    for (int ni = 0; ni < 4; ++ni)
#pragma unroll
      for (int r = 0; r < 4; ++r) {
        const int row = m0 + wm * 64 + mi * 16 + quad * 4 + r;
        const int col = n0 + wn * 64 + ni * 16 + lm;
        const float v = acc[mi][ni][r];
        if (EPI == 0) {
          ((__hip_bfloat16*)Cv)[(size_t)row * N + col] = __float2bfloat16(v);
        } else if (EPI == 1) {
          __hip_bfloat16* H = (__hip_bfloat16*)Cv;
          const float u = __bfloat162float(H[(size_t)row * N + col]);
          const float sg = v / (1.0f + __expf(-v));
          H[(size_t)row * N + col] = __float2bfloat16(sg * u);
        } else {
          ((float*)Cv)[(size_t)row * N + col] = v;
        }
      }
}

extern "C" void kernel_launch(void* const* d_in, const int* in_sizes, int n_in,
                              void* d_out, int out_size, void* d_ws, size_t ws_size,
                              hipStream_t stream) {
  const float* x   = (const float*)d_in[0];
  const int*   gqw = (const int*)d_in[1];
  const float* gsc = (const float*)d_in[2];
  const int*   gqz = (const int*)d_in[3];
  const int*   uqw = (const int*)d_in[4];
  const float* usc = (const float*)d_in[5];
  const int*   uqz = (const int*)d_in[6];
  const int*   dqw = (const int*)d_in[7];
  const float* dsc = (const float*)d_in[8];
  const int*   dqz = (const int*)d_in[9];
  float* out = (float*)d_out;

  // ws layout (214 MB total):
  //   xb   : T_TOK*KDIM bf16      = 33,554,432 B
  //   wbuf : IDIM*KDIM bf16       = 90,177,536 B (reused for up/gate/down^T)
  //   h    : T_TOK*IDIM bf16      = 90,177,536 B
  char* ws = (char*)d_ws;
  __hip_bfloat16* xb   = (__hip_bfloat16*)ws;
  __hip_bfloat16* wbuf = (__hip_bfloat16*)(ws + 33554432);
  __hip_bfloat16* h    = (__hip_bfloat16*)(ws + 33554432 + 90177536);

  k_f32_to_bf16<<<16384, 256, 0, stream>>>((const float4*)x, (ushort4*)xb,
                                           (T_TOK * KDIM) / 4);

  dim3 dqg(IDIM / 64, KDIM / 64);    // (172, 64)
  dim3 dqd(ODIM / 64, IDIM / 64);    // (64, 172)
  dim3 g1(IDIM / 128, T_TOK / 128);  // (86, 32)
  dim3 g2(ODIM / 128, T_TOK / 128);  // (32, 32)

  // up: u = x @ Wu^T  -> h (bf16)
  k_dequant_t<<<dqg, 256, 0, stream>>>(uqw, usc, uqz, wbuf, KDIM, IDIM);
  k_gemm_bt<0><<<g1, 256, 0, stream>>>(xb, wbuf, (void*)h, T_TOK, IDIM, KDIM);
  // gate: h = silu(x @ Wg^T) * h
  k_dequant_t<<<dqg, 256, 0, stream>>>(gqw, gsc, gqz, wbuf, KDIM, IDIM);
  k_gemm_bt<1><<<g1, 256, 0, stream>>>(xb, wbuf, (void*)h, T_TOK, IDIM, KDIM);
  // down: out = h @ Wd^T (f32)
  k_dequant_t<<<dqd, 256, 0, stream>>>(dqw, dsc, dqz, wbuf, IDIM, ODIM);
  k_gemm_bt<2><<<g2, 256, 0, stream>>>(h, wbuf, (void*)out, T_TOK, ODIM, IDIM);
}

// Round 5
// 1453.899 us; speedup vs baseline: 1.4108x; 1.0754x over previous
//
#include <hip/hip_runtime.h>
#include <hip/hip_bf16.h>
#include <hip/hip_fp16.h>

// Problem dims (fixed for QuantLlamaMLP_549755813920)
#define T_TOK 4096   // tokens = 2*2048
#define KDIM  4096   // in_features
#define IDIM  11008  // intermediate
#define ODIM  4096   // out_features

typedef _Float16 f16x8 __attribute__((ext_vector_type(8)));
typedef __fp16   h16x2 __attribute__((ext_vector_type(2)));  // cvt_pkrtz return type
typedef float    f32x4 __attribute__((ext_vector_type(4)));
typedef float    f32x2 __attribute__((ext_vector_type(2)));

// async global->LDS, 16B per lane; LDS dest = wave-uniform base + lane*16
__device__ __forceinline__ void glds16(const void* g, void* l) {
  __builtin_amdgcn_global_load_lds(
      (const __attribute__((address_space(1))) void*)g,
      (__attribute__((address_space(3))) void*)l, 16, 0, 0);
}

// ---------------- x: f32 -> f16 ----------------
__global__ void k_f32_to_f16(const float4* __restrict__ x,
                             ushort4* __restrict__ o, int n4) {
  int i = blockIdx.x * 256 + threadIdx.x;
  if (i >= n4) return;
  float4 v = x[i];
  __half h0 = __float2half(v.x), h1 = __float2half(v.y);
  __half h2v = __float2half(v.z), h3 = __float2half(v.w);
  ushort4 r;
  r.x = *(unsigned short*)&h0; r.y = *(unsigned short*)&h1;
  r.z = *(unsigned short*)&h2v; r.w = *(unsigned short*)&h3;
  o[i] = r;
}

// ------- repack int4 -> fp8 e4m3 (q-z), transposed to [N][K] --------------
// (q-z) in [-15,15] is EXACT in e4m3. Scale applied later in GEMM staging.
// qw: [K, N/8] int32, qz: [K/128, N/8] int32 -> bq: [N][K] fp8
__global__ void k_repack_fp8(const int* __restrict__ qw,
                             const int* __restrict__ qz,
                             unsigned char* __restrict__ bq,
                             int K, int N) {
  __shared__ __align__(16) unsigned char tile[64][80];  // [n][k], 80%16==0
  const int n0 = blockIdx.x * 64;
  const int k0 = blockIdx.y * 64;
  const int t  = threadIdx.x;
  const int Nw = N >> 3;
  const int grp = k0 >> 7;  // 64-tile always within one 128-group
  const int jj = t & 7;
  const int zword = qz[(size_t)grp * Nw + (n0 >> 3) + jj];
#pragma unroll
  for (int r = 0; r < 2; ++r) {
    const int kk = (t >> 3) + r * 32;
    const int word = qw[(size_t)(k0 + kk) * Nw + (n0 >> 3) + jj];
#pragma unroll
    for (int i = 0; i < 8; i += 2) {
      const float v0 = (float)(((word >> (4 * i)) & 0xF) - ((zword >> (4 * i)) & 0xF));
      const float v1 = (float)(((word >> (4 * i + 4)) & 0xF) - ((zword >> (4 * i + 4)) & 0xF));
      const int p = __builtin_amdgcn_cvt_pk_fp8_f32(v0, v1, 0, false);
      tile[jj * 8 + i][kk]     = (unsigned char)(p & 0xFF);
      tile[jj * 8 + i + 1][kk] = (unsigned char)((p >> 8) & 0xFF);
    }
  }
  __syncthreads();
  const int n  = t >> 2;
  const int kc = (t & 3) * 16;
  int4 v = *(const int4*)&tile[n][kc];
  *(int4*)(bq + (size_t)(n0 + n) * K + k0 + kc) = v;
}

// dequant 16 fp8 (in uint4) * s -> 16 f16 stored at 16B-aligned dst
__device__ __forceinline__ void dq16(uint4 w, float s, __half* dst) {
  h16x2 r[8];
  const unsigned int ws[4] = {w.x, w.y, w.z, w.w};
#pragma unroll
  for (int d = 0; d < 4; ++d) {
    f32x2 lo = __builtin_amdgcn_cvt_pk_f32_fp8((int)ws[d], false);
    f32x2 hi = __builtin_amdgcn_cvt_pk_f32_fp8((int)ws[d], true);
    r[d * 2]     = __builtin_amdgcn_cvt_pkrtz(lo.x * s, lo.y * s);
    r[d * 2 + 1] = __builtin_amdgcn_cvt_pkrtz(hi.x * s, hi.y * s);
  }
  *(uint4*)dst       = *(const uint4*)&r[0];
  *(uint4*)(dst + 8) = *(const uint4*)&r[4];
}

// ---------------- GEMM: C[M,N] = A[M,K] @ Bq[N,K]^T (fp8 B, f16 MFMA) -----
// R2: grouped swizzle GM=16. R3: BK=64, two stages/barrier-pair.
// R4: B kept fp8 through L2/L3 (half fill bytes), dequant (*s, group=128)
//     during LDS staging; Bs rows padded to 40 f16 (80 B) to break bank
//     conflicts; next-iter B bytes prefetched into registers during the
//     MFMA phase (in flight a full window before the barrier drain).
// EPI 0: C f16 = acc          (up -> h)
// EPI 1: C f16 = silu(acc)*C  (gate, reads u from h, writes h)
// EPI 2: C f32 = acc          (down -> d_out)
template <int EPI>
__global__ __launch_bounds__(256, 3)
void k_gemm_q(const __half* __restrict__ A,
              const unsigned char* __restrict__ Bq,
              const float* __restrict__ sc,
              void* __restrict__ Cv, int M, int N, int K) {
  __shared__ __align__(16) __half As[2][128 * 32];
  __shared__ __align__(16) __half Bs[2][128 * 40];  // padded: 40 f16 = 80 B rows
  // ---- grouped swizzle: bid -> (mb, nb) ----
  const int nblk = gridDim.x;
  const int bid  = blockIdx.y * nblk + blockIdx.x;
  const int GM   = 16;
  const int band_sz = GM * nblk;
  const int band = bid / band_sz;
  const int rrem = bid - band * band_sz;
  const int nb   = rrem / GM;
  const int mb   = band * GM + (rrem - nb * GM);
  const int n0 = nb * 128;
  const int m0 = mb * 128;

  const int t = threadIdx.x;
  const int w = t >> 6;
  const int lane = t & 63;
  const int quad = lane >> 4;
  const int lm = lane & 15;
  const int wm = w >> 1;
  const int wn = w & 1;
  f32x4 acc[4][4] = {};

  // A staging (glds16): wave w rows [w*32, w*32+32)
  const int lrow = lane >> 2;
  const int lkc  = (lane & 3) * 8;
  const __half* Ag0 = A + (size_t)(m0 + w * 32 + lrow) * K + lkc;
  const __half* Ag1 = Ag0 + (size_t)16 * K;
  const int lo0 = (w * 32) * 32;
  const int lo1 = (w * 32 + 16) * 32;

  // B staging (register dequant): thread -> (row = t>>1, half = t&1)
  const int brow = t >> 1;
  const int bhalf = t & 1;
  const unsigned char* bg = Bq + (size_t)(n0 + brow) * K + bhalf * 16;
  __half* bdst0 = &Bs[0][brow * 40 + bhalf * 16];
  __half* bdst1 = &Bs[1][brow * 40 + bhalf * 16];

  float s = 0.0f;
  uint4 bc0 = *(const uint4*)(bg);        // k0=0, stage 0
  uint4 bc1 = *(const uint4*)(bg + 32);   // k0=0, stage 1

  for (int k0 = 0; k0 < K; k0 += 64) {
    if ((k0 & 127) == 0) s = sc[(size_t)(k0 >> 7) * N + n0 + brow];
    __syncthreads();  // prev fragments consumed; drains B prefetch
    glds16(Ag0 + k0, &As[0][lo0]);
    glds16(Ag1 + k0, &As[0][lo1]);
    glds16(Ag0 + k0 + 32, &As[1][lo0]);
    glds16(Ag1 + k0 + 32, &As[1][lo1]);
    dq16(bc0, s, bdst0);
    dq16(bc1, s, bdst1);
    __syncthreads();  // drains A glds16 + ds_writes
    const int kn = (k0 + 64 < K) ? (k0 + 64) : 0;  // harmless reload on last
    bc0 = *(const uint4*)(bg + kn);        // prefetch: in flight across MFMA
    bc1 = *(const uint4*)(bg + kn + 32);
#pragma unroll
    for (int h = 0; h < 2; ++h) {
      f16x8 af[4], bfr[4];
#pragma unroll
      for (int mi = 0; mi < 4; ++mi)
        af[mi] = *(const f16x8*)&As[h][(wm * 64 + mi * 16 + lm) * 32 + quad * 8];
#pragma unroll
      for (int ni = 0; ni < 4; ++ni)
        bfr[ni] = *(const f16x8*)&Bs[h][(wn * 64 + ni * 16 + lm) * 40 + quad * 8];
#pragma unroll
      for (int mi = 0; mi < 4; ++mi)
#pragma unroll
        for (int ni = 0; ni < 4; ++ni)
          acc[mi][ni] = __builtin_amdgcn_mfma_f32_16x16x32_f16(
              af[mi], bfr[ni], acc[mi][ni], 0, 0, 0);
    }
  }

  // epilogue: C/D layout col=lane&15, row=quad*4+reg
#pragma unroll
  for (int mi = 0; mi < 4; ++mi)
#pragma unroll
    for (int ni = 0; ni < 4; ++ni)
#pragma unroll
      for (int r = 0; r < 4; ++r) {
        const int row = m0 + wm * 64 + mi * 16 + quad * 4 + r;
        const int col = n0 + wn * 64 + ni * 16 + lm;
        const float v = acc[mi][ni][r];
        if (EPI == 0) {
          ((__half*)Cv)[(size_t)row * N + col] = __float2half(v);
        } else if (EPI == 1) {
          __half* H = (__half*)Cv;
          const float u = __half2float(H[(size_t)row * N + col]);
          const float sg = v / (1.0f + __expf(-v));
          H[(size_t)row * N + col] = __float2half(sg * u);
        } else {
          ((float*)Cv)[(size_t)row * N + col] = v;
        }
      }
}

extern "C" void kernel_launch(void* const* d_in, const int* in_sizes, int n_in,
                              void* d_out, int out_size, void* d_ws, size_t ws_size,
                              hipStream_t stream) {
  const float* x   = (const float*)d_in[0];
  const int*   gqw = (const int*)d_in[1];
  const float* gsc = (const float*)d_in[2];
  const int*   gqz = (const int*)d_in[3];
  const int*   uqw = (const int*)d_in[4];
  const float* usc = (const float*)d_in[5];
  const int*   uqz = (const int*)d_in[6];
  const int*   dqw = (const int*)d_in[7];
  const float* dsc = (const float*)d_in[8];
  const int*   dqz = (const int*)d_in[9];
  float* out = (float*)d_out;

  // ws layout (~169 MB):
  //   xb  : T_TOK*KDIM f16   = 33,554,432 B
  //   bq  : IDIM*KDIM  fp8   = 45,088,768 B (reused up/gate/down)
  //   h   : T_TOK*IDIM f16   = 90,177,536 B
  char* ws = (char*)d_ws;
  __half*        xb = (__half*)ws;
  unsigned char* bq = (unsigned char*)(ws + 33554432);
  __half*        h  = (__half*)(ws + 33554432 + 45088768);

  k_f32_to_f16<<<16384, 256, 0, stream>>>((const float4*)x, (ushort4*)xb,
                                          (T_TOK * KDIM) / 4);

  dim3 rpg(IDIM / 64, KDIM / 64);    // (172, 64)
  dim3 rpd(ODIM / 64, IDIM / 64);    // (64, 172)
  dim3 g1(IDIM / 128, T_TOK / 128);  // (86, 32)
  dim3 g2(ODIM / 128, T_TOK / 128);  // (32, 32)

  // up: u = x @ Wu^T  -> h (f16)
  k_repack_fp8<<<rpg, 256, 0, stream>>>(uqw, uqz, bq, KDIM, IDIM);
  k_gemm_q<0><<<g1, 256, 0, stream>>>(xb, bq, usc, (void*)h, T_TOK, IDIM, KDIM);
  // gate: h = silu(x @ Wg^T) * h
  k_repack_fp8<<<rpg, 256, 0, stream>>>(gqw, gqz, bq, KDIM, IDIM);
  k_gemm_q<1><<<g1, 256, 0, stream>>>(xb, bq, gsc, (void*)h, T_TOK, IDIM, KDIM);
  // down: out = h @ Wd^T (f32)
  k_repack_fp8<<<rpd, 256, 0, stream>>>(dqw, dqz, bq, IDIM, ODIM);
  k_gemm_q<2><<<g2, 256, 0, stream>>>(h, bq, dsc, (void*)out, T_TOK, ODIM, IDIM);
}